// Round 1
// baseline (169.562 us; speedup 1.0000x reference)
//
#include <hip/hip_runtime.h>
#include <math.h>

#define NU_L 2000
#define NU_V 1500
#define EPSF 1e-6f
#define PIF  3.14159265358979323846f

__device__ __forceinline__ float poly5(float c0, float c1, float c2, float c3, float c4, float z) {
    // sum_{i=1}^{5} c_{i-1} * z^i  (Horner)
    float p = c4;
    p = fmaf(p, z, c3);
    p = fmaf(p, z, c2);
    p = fmaf(p, z, c1);
    p = fmaf(p, z, c0);
    return p * z;
}

// 1/sqrt(cx + i*cy), principal branch.
// csqrt(c) = (t, copysign(v, cy)) with t=sqrt((r+cx)/2), v=sqrt((r-cx)/2), r=|c|.
// |csqrt(c)|^2 = r, so 1/csqrt(c) = conj(csqrt(c))/r.
__device__ __forceinline__ void inv_csqrt(float cx, float cy, float& ox, float& oy) {
    float r = sqrtf(fmaf(cx, cx, cy * cy));
    float t = sqrtf(0.5f * fmaxf(r + cx, 0.0f));
    float v = sqrtf(0.5f * fmaxf(r - cx, 0.0f));
    float sy = copysignf(v, cy);
    float invr = 1.0f / r;
    ox = t * invr;
    oy = -sy * invr;
}

__global__ __launch_bounds__(256) void adsbh_kernel(
    const float* __restrict__ pa, const float* __restrict__ pb,
    const float* __restrict__ zs_arr, float* __restrict__ out, int B)
{
    const int bid = blockIdx.x;
    const int tid = threadIdx.x;
    if (bid >= B) return;

    const float a0 = pa[0], a1 = pa[1], a2 = pa[2], a3 = pa[3], a4 = pa[4];
    const float b0 = pb[0], b1 = pb[1], b2 = pb[2], b3 = pb[3], b4 = pb[4];

    const float zs  = zs_arr[bid];
    const float zs2 = zs * zs;
    const float zs4 = zs2 * zs2;

    // f(zs) — real positive
    const float fzs = (1.0f - zs4) * expf(poly5(a0, a1, a2, a3, a4, zs));

    const float hL = (1.0f - 2.0f * EPSF) / (float)(NU_L - 1);
    const float hV = (1.0f - 2.0f * EPSF) / (float)(NU_V - 1);

    float Lre = 0.0f, Lim = 0.0f, Vre = 0.0f, Vim = 0.0f;

    // ---------------- integrate_L ----------------
    // denom = zs^4*f(z) / (z^4*f(zs) + eps(1+i)) - 1 + eps(1+i)
    // integrand = sqrt(g(z)) / csqrt(denom)
    for (int k = tid; k < NU_L; k += 256) {
        float u  = fmaf((float)k, hL, EPSF);
        float z  = zs * u;
        float z2 = z * z;
        float z4 = z2 * z2;
        float omz4 = 1.0f - z4;
        float Pa = poly5(a0, a1, a2, a3, a4, z);
        float Pb = poly5(b0, b1, b2, b3, b4, z);
        float fz = omz4 * expf(Pa);
        float gz = expf(Pb) / omz4;

        float A  = zs4 * fz;                       // real numerator
        float dx = fmaf(z4, fzs, EPSF);            // denom of ratio, real part
        float dy = EPSF;                           // imag part
        float inv = 1.0f / fmaf(dx, dx, dy * dy);
        float cx = A * dx * inv - 1.0f + EPSF;     // Re(denom)
        float cy = -A * dy * inv + EPSF;           // Im(denom)

        float ox, oy;
        inv_csqrt(cx, cy, ox, oy);

        float sg = sqrtf(gz);                      // sqrt of positive real
        float w  = (k == 0 || k == NU_L - 1) ? 0.5f : 1.0f;
        float ws = w * sg;
        Lre = fmaf(ws, ox, Lre);
        Lim = fmaf(ws, oy, Lim);
    }

    // ---------------- integrate_V ----------------
    // inner = 1 - z^4*f(zs) / (zs^4*f(z) + eps(1+i)) + eps(1+i)
    // term  = sqrt(f(z)*g(z)) / csqrt(inner) - 1
    // integrand = term / (z^2 + eps(1+i))
    for (int k = tid; k < NU_V; k += 256) {
        float u  = fmaf((float)k, hV, EPSF);
        float z  = zs * u;
        float z2 = z * z;
        float z4 = z2 * z2;
        float omz4 = 1.0f - z4;
        float Pa = poly5(a0, a1, a2, a3, a4, z);
        float Pb = poly5(b0, b1, b2, b3, b4, z);
        float fz = omz4 * expf(Pa);
        float gz = expf(Pb) / omz4;

        float Bv = z4 * fzs;                       // real numerator
        float dx = fmaf(zs4, fz, EPSF);
        float dy = EPSF;
        float inv = 1.0f / fmaf(dx, dx, dy * dy);
        float icx = 1.0f - Bv * dx * inv + EPSF;   // Re(inner)
        float icy = Bv * dy * inv + EPSF;          // Im(inner)  (= -ratio.im + eps)

        float ox, oy;
        inv_csqrt(icx, icy, ox, oy);

        float F   = sqrtf(fz * gz);                // = e^{(Pa+Pb)/2} up to rounding
        float tre = fmaf(F, ox, -1.0f);
        float tim = F * oy;

        float ddx = z2 + EPSF, ddy = EPSF;         // z^2 + eps(1+i)
        float inv2 = 1.0f / fmaf(ddx, ddx, ddy * ddy);
        float vre = (tre * ddx + tim * ddy) * inv2;
        float vim = (tim * ddx - tre * ddy) * inv2;

        float w = (k == 0 || k == NU_V - 1) ? 0.5f : 1.0f;
        Vre = fmaf(w, vre, Vre);
        Vim = fmaf(w, vim, Vim);
    }

    // ---------------- block reduction (4 waves of 64) ----------------
    for (int off = 32; off > 0; off >>= 1) {
        Lre += __shfl_down(Lre, off);
        Lim += __shfl_down(Lim, off);
        Vre += __shfl_down(Vre, off);
        Vim += __shfl_down(Vim, off);
    }
    __shared__ float4 wsum[4];
    const int lane = tid & 63;
    const int wid  = tid >> 6;
    if (lane == 0) wsum[wid] = make_float4(Lre, Lim, Vre, Vim);
    __syncthreads();
    if (tid == 0) {
        float4 t = wsum[0];
        t.x += wsum[1].x + wsum[2].x + wsum[3].x;
        t.y += wsum[1].y + wsum[2].y + wsum[3].y;
        t.z += wsum[1].z + wsum[2].z + wsum[3].z;
        t.w += wsum[1].w + wsum[2].w + wsum[3].w;

        const float twopi = 2.0f * PIF;
        const float sL = (2.0f / PIF) * zs * hL;   // (2/pi) * zs * du
        const float sV = twopi * zs * hV;          // 2*pi * zs * du
        out[0 * B + bid] = t.x * sL;
        out[1 * B + bid] = t.y * sL;
        out[2 * B + bid] = t.z * sV - twopi / zs;  // minus V_disc (real)
        out[3 * B + bid] = t.w * sV;
    }
}

extern "C" void kernel_launch(void* const* d_in, const int* in_sizes, int n_in,
                              void* d_out, int out_size, void* d_ws, size_t ws_size,
                              hipStream_t stream) {
    const float* a  = (const float*)d_in[0];
    const float* b  = (const float*)d_in[1];
    const float* zs = (const float*)d_in[2];
    float* out = (float*)d_out;
    const int B = in_sizes[2];
    adsbh_kernel<<<B, 256, 0, stream>>>(a, b, zs, out, B);
}

// Round 2
// 104.260 us; speedup vs baseline: 1.6263x; 1.6263x over previous
//
#include <hip/hip_runtime.h>
#include <math.h>

#define NU_L 2000
#define NU_V 1500
#define EPSF 1e-6f
#define PIF   3.14159265358979323846f
#define LOG2E 1.44269504088896340736f

// ---- raw hardware transcendentals (single v_* instruction, ~1 ulp) ----
__device__ __forceinline__ float rcp_raw(float x)  { return __builtin_amdgcn_rcpf(x); }
__device__ __forceinline__ float sqrt_raw(float x) { return __builtin_amdgcn_sqrtf(x); }
__device__ __forceinline__ float rsq_raw(float x)  { return __builtin_amdgcn_rsqf(x); }
__device__ __forceinline__ float exp2_raw(float x) {
#if __has_builtin(__builtin_amdgcn_exp2f)
    return __builtin_amdgcn_exp2f(x);
#else
    return exp2f(x);
#endif
}
// rcp + 1 Newton step: ~0.5-1 ulp, used where the result feeds a
// catastrophic cancellation (denom/inner ratio).
__device__ __forceinline__ float rcp_nr(float x) {
    float r = __builtin_amdgcn_rcpf(x);
    float e = fmaf(-x, r, 1.0f);
    return fmaf(r, e, r);
}

__device__ __forceinline__ float poly5(float c0, float c1, float c2, float c3, float c4, float z) {
    // sum_{i=1}^{5} c_{i-1} * z^i  (Horner)
    float p = c4;
    p = fmaf(p, z, c3);
    p = fmaf(p, z, c2);
    p = fmaf(p, z, c1);
    p = fmaf(p, z, c0);
    return p * z;
}

// 1/sqrt(cx + i*cy), principal branch.
// csqrt(c) = (t, copysign(v, cy)); 1/csqrt(c) = conj(csqrt(c))/|c|.
__device__ __forceinline__ void inv_csqrt(float cx, float cy, float& ox, float& oy) {
    float r = sqrt_raw(fmaf(cx, cx, cy * cy));
    float t = sqrt_raw(fmaxf(0.5f * (r + cx), 0.0f));
    float v = sqrt_raw(fmaxf(0.5f * (r - cx), 0.0f));
    float sy = copysignf(v, cy);
    float invr = rcp_raw(r);            // error-linear in result: raw rcp ok
    ox = t * invr;
    oy = -sy * invr;
}

__global__ __launch_bounds__(256) void adsbh_kernel(
    const float* __restrict__ pa, const float* __restrict__ pb,
    const float* __restrict__ zs_arr, float* __restrict__ out, int B)
{
    const int bid = blockIdx.x;
    const int tid = threadIdx.x;
    if (bid >= B) return;

    // coefficients pre-scaled by log2(e): exp(P(c,z)) == exp2(P(c*log2e, z))
    const float a0 = pa[0] * LOG2E, a1 = pa[1] * LOG2E, a2 = pa[2] * LOG2E,
                a3 = pa[3] * LOG2E, a4 = pa[4] * LOG2E;
    const float b0 = pb[0] * LOG2E, b1 = pb[1] * LOG2E, b2 = pb[2] * LOG2E,
                b3 = pb[3] * LOG2E, b4 = pb[4] * LOG2E;

    const float zs  = zs_arr[bid];
    const float zs2 = zs * zs;
    const float zs4 = zs2 * zs2;

    // f(zs) — real positive
    const float fzs = (1.0f - zs4) * exp2_raw(poly5(a0, a1, a2, a3, a4, zs));

    const float hL = (1.0f - 2.0f * EPSF) / (float)(NU_L - 1);
    const float hV = (1.0f - 2.0f * EPSF) / (float)(NU_V - 1);

    float Lre = 0.0f, Lim = 0.0f, Vre = 0.0f, Vim = 0.0f;

    // ---------------- integrate_L ----------------
    // denom = zs^4*f(z) / (z^4*f(zs) + eps(1+i)) - 1 + eps(1+i)
    // integrand = sqrt(g(z)) / csqrt(denom)
    for (int k = tid; k < NU_L; k += 256) {
        float u  = fmaf((float)k, hL, EPSF);
        float z  = zs * u;
        float z2 = z * z;
        float z4 = z2 * z2;
        float omz4 = 1.0f - z4;
        float Pa = poly5(a0, a1, a2, a3, a4, z);   // already *log2e
        float Pb = poly5(b0, b1, b2, b3, b4, z);
        float fz = omz4 * exp2_raw(Pa);
        // sqrt(g) = exp2(Pb/2) * rsqrt(1 - z^4)   (g > 0 real)
        float sg = exp2_raw(0.5f * Pb) * rsq_raw(omz4);

        float A  = zs4 * fz;                       // real numerator
        float dx = fmaf(z4, fzs, EPSF);            // denom of ratio, real part
        float inv = rcp_nr(fmaf(dx, dx, EPSF * EPSF));
        float cx = A * dx * inv - 1.0f + EPSF;     // Re(denom)
        float cy = -A * EPSF * inv + EPSF;         // Im(denom)

        float ox, oy;
        inv_csqrt(cx, cy, ox, oy);

        float w  = (k == 0 || k == NU_L - 1) ? 0.5f : 1.0f;
        float ws = w * sg;
        Lre = fmaf(ws, ox, Lre);
        Lim = fmaf(ws, oy, Lim);
    }

    // ---------------- integrate_V ----------------
    // inner = 1 - z^4*f(zs) / (zs^4*f(z) + eps(1+i)) + eps(1+i)
    // term  = sqrt(f(z)*g(z)) / csqrt(inner) - 1
    // integrand = term / (z^2 + eps(1+i))
    for (int k = tid; k < NU_V; k += 256) {
        float u  = fmaf((float)k, hV, EPSF);
        float z  = zs * u;
        float z2 = z * z;
        float z4 = z2 * z2;
        float omz4 = 1.0f - z4;
        float Pa = poly5(a0, a1, a2, a3, a4, z);
        float Pb = poly5(b0, b1, b2, b3, b4, z);
        float fz = omz4 * exp2_raw(Pa);
        // sqrt(f*g) = exp2((Pa+Pb)/2)  ((1-z^4) cancels exactly)
        float F  = exp2_raw(0.5f * (Pa + Pb));

        float Bv = z4 * fzs;                       // real numerator
        float dx = fmaf(zs4, fz, EPSF);
        float inv = rcp_nr(fmaf(dx, dx, EPSF * EPSF));
        float icx = 1.0f - Bv * dx * inv + EPSF;   // Re(inner)
        float icy = Bv * EPSF * inv + EPSF;        // Im(inner)

        float ox, oy;
        inv_csqrt(icx, icy, ox, oy);

        float tre = fmaf(F, ox, -1.0f);
        float tim = F * oy;

        float ddx = z2 + EPSF;                     // z^2 + eps(1+i)
        float inv2 = rcp_nr(fmaf(ddx, ddx, EPSF * EPSF));
        float vre = (tre * ddx + tim * EPSF) * inv2;
        float vim = (tim * ddx - tre * EPSF) * inv2;

        float w = (k == 0 || k == NU_V - 1) ? 0.5f : 1.0f;
        Vre = fmaf(w, vre, Vre);
        Vim = fmaf(w, vim, Vim);
    }

    // ---------------- block reduction (4 waves of 64) ----------------
    for (int off = 32; off > 0; off >>= 1) {
        Lre += __shfl_down(Lre, off);
        Lim += __shfl_down(Lim, off);
        Vre += __shfl_down(Vre, off);
        Vim += __shfl_down(Vim, off);
    }
    __shared__ float4 wsum[4];
    const int lane = tid & 63;
    const int wid  = tid >> 6;
    if (lane == 0) wsum[wid] = make_float4(Lre, Lim, Vre, Vim);
    __syncthreads();
    if (tid == 0) {
        float4 t = wsum[0];
        t.x += wsum[1].x + wsum[2].x + wsum[3].x;
        t.y += wsum[1].y + wsum[2].y + wsum[3].y;
        t.z += wsum[1].z + wsum[2].z + wsum[3].z;
        t.w += wsum[1].w + wsum[2].w + wsum[3].w;

        const float twopi = 2.0f * PIF;
        const float sL = (2.0f / PIF) * zs * hL;   // (2/pi) * zs * du
        const float sV = twopi * zs * hV;          // 2*pi * zs * du
        out[0 * B + bid] = t.x * sL;
        out[1 * B + bid] = t.y * sL;
        out[2 * B + bid] = t.z * sV - twopi / zs;  // minus V_disc (real)
        out[3 * B + bid] = t.w * sV;
    }
}

extern "C" void kernel_launch(void* const* d_in, const int* in_sizes, int n_in,
                              void* d_out, int out_size, void* d_ws, size_t ws_size,
                              hipStream_t stream) {
    const float* a  = (const float*)d_in[0];
    const float* b  = (const float*)d_in[1];
    const float* zs = (const float*)d_in[2];
    float* out = (float*)d_out;
    const int B = in_sizes[2];
    adsbh_kernel<<<B, 256, 0, stream>>>(a, b, zs, out, B);
}

// Round 3
// 102.722 us; speedup vs baseline: 1.6507x; 1.0150x over previous
//
#include <hip/hip_runtime.h>
#include <math.h>

#define NU_L 2000
#define NU_V 1500
#define EPSF 1e-6f
#define EPS2 1e-12f
#define PIF   3.14159265358979323846f
#define LOG2E 1.44269504088896340736f

// ---- raw hardware transcendentals (single v_* instruction, ~1 ulp) ----
__device__ __forceinline__ float rcp_raw(float x)  { return __builtin_amdgcn_rcpf(x); }
__device__ __forceinline__ float sqrt_raw(float x) { return __builtin_amdgcn_sqrtf(x); }
__device__ __forceinline__ float rsq_raw(float x)  { return __builtin_amdgcn_rsqf(x); }
__device__ __forceinline__ float exp2_raw(float x) {
#if __has_builtin(__builtin_amdgcn_exp2f)
    return __builtin_amdgcn_exp2f(x);
#else
    return exp2f(x);
#endif
}

// Estrin: H = c0 + c1 z + c2 z^2 + c3 z^3 + c4 z^4  (P(z) = z*H)
__device__ __forceinline__ float poly_h(float c0, float c1, float c2, float c3, float c4,
                                        float z, float z2, float z4) {
    float q01 = fmaf(c1, z, c0);
    float q23 = fmaf(c3, z, c2);
    float t   = fmaf(z2, q23, q01);
    return fmaf(c4, z4, t);
}

// s / csqrt(nx + i*ny), principal branch, s > 0 real.
// csqrt(n) = (t, copysign(v,ny)); 1/csqrt(n) = conj(csqrt(n))/|n|; |n| via rsq.
__device__ __forceinline__ void inv_csqrt_scaled(float nx, float ny, float s,
                                                 float& ox, float& oy) {
    float r2 = fmaf(nx, nx, ny * ny);
    float ir = rsq_raw(r2);                 // 1/|n|
    float r  = r2 * ir;                     // |n|
    float t  = sqrt_raw(fmaxf(0.5f * (r + nx), 0.0f));
    float v  = sqrt_raw(fmaxf(0.5f * (r - nx), 0.0f));
    float sy = copysignf(v, ny);
    float si = s * ir;
    ox = t * si;
    oy = -sy * si;
}

// One L-grid point. denom = zs^4 f(z)/(z^4 f(zs)+eps(1+i)) - 1 + eps(1+i)
//   = num/D with D = dx^2+eps^2 (>0 real), so 1/csqrt(denom) = sqrt(D)/csqrt(num).
__device__ __forceinline__ void point_L(int kk, float zs, float zs4, float fzs, float hL,
    float a0, float a1, float a2, float a3, float a4,
    float b0, float b1, float b2, float b3, float b4,
    float& Lre, float& Lim)
{
    const bool act  = (kk < NU_L);
    const bool edge = (kk == 0) | (kk == NU_L - 1);
    float w = act ? (edge ? 0.5f : 1.0f) : 0.0f;
    float u = act ? fmaf((float)kk, hL, EPSF) : 0.5f;

    float z = zs * u, z2 = z * z, z4 = z2 * z2;
    float omz4 = 1.0f - z4;
    float Pa = z * poly_h(a0, a1, a2, a3, a4, z, z2, z4);   // already *log2e
    float Pb = z * poly_h(b0, b1, b2, b3, b4, z, z2, z4);
    float fz = omz4 * exp2_raw(Pa);
    float sg = exp2_raw(0.5f * Pb) * rsq_raw(omz4);         // sqrt(g(z))

    float A  = zs4 * fz;
    float dx = fmaf(z4, fzs, EPSF);
    float D  = fmaf(dx, dx, EPS2);
    float nx = fmaf(EPSF, D, fmaf(A, dx, -D));              // A*dx - D(1-eps)
    float ny = EPSF * (D - A);                              // eps*(D - A)
    float sD = sqrt_raw(D);

    float ox, oy;
    inv_csqrt_scaled(nx, ny, sD, ox, oy);

    float ws = w * sg;
    Lre = fmaf(ws, ox, Lre);
    Lim = fmaf(ws, oy, Lim);
}

// One V-grid point. inner = 1 - z^4 f(zs)/(zs^4 f(z)+eps(1+i)) + eps(1+i) = num/D.
// term = F/csqrt(inner) - 1, F = sqrt(f g) = exp2((Pa+Pb)/2); then /(z^2+eps(1+i)).
__device__ __forceinline__ void point_V(int kk, float zs, float zs4, float fzs, float hV,
    float a0, float a1, float a2, float a3, float a4,
    float b0, float b1, float b2, float b3, float b4,
    float& Vre, float& Vim)
{
    const bool act  = (kk < NU_V);
    const bool edge = (kk == 0) | (kk == NU_V - 1);
    float w = act ? (edge ? 0.5f : 1.0f) : 0.0f;
    float u = act ? fmaf((float)kk, hV, EPSF) : 0.5f;

    float z = zs * u, z2 = z * z, z4 = z2 * z2;
    float omz4 = 1.0f - z4;
    float Pa = z * poly_h(a0, a1, a2, a3, a4, z, z2, z4);
    float Pb = z * poly_h(b0, b1, b2, b3, b4, z, z2, z4);
    float fz = omz4 * exp2_raw(Pa);
    float F  = exp2_raw(0.5f * (Pa + Pb));                  // sqrt(f*g), (1-z^4) cancels

    float Bv = z4 * fzs;
    float dx = fmaf(zs4, fz, EPSF);
    float D  = fmaf(dx, dx, EPS2);
    float nx = fmaf(EPSF, D, fmaf(-Bv, dx, D));             // D(1+eps) - Bv*dx
    float ny = EPSF * (Bv + D);                             // eps*(Bv + D)
    float sD = sqrt_raw(D);

    float ox, oy;
    inv_csqrt_scaled(nx, ny, F * sD, ox, oy);               // = F/csqrt(inner)

    float tre = ox - 1.0f;
    float tim = oy;

    float ddx = z2 + EPSF;                                  // z^2 + eps(1+i)
    float idn = rcp_raw(fmaf(ddx, ddx, EPS2));              // error-linear: raw rcp ok
    float vre = fmaf(tre, ddx,  tim * EPSF) * idn;
    float vim = fmaf(tim, ddx, -tre * EPSF) * idn;

    Vre = fmaf(w, vre, Vre);
    Vim = fmaf(w, vim, Vim);
}

__global__ __launch_bounds__(256) void adsbh_kernel(
    const float* __restrict__ pa, const float* __restrict__ pb,
    const float* __restrict__ zs_arr, float* __restrict__ out, int B)
{
    const int bid = blockIdx.x;
    const int tid = threadIdx.x;
    if (bid >= B) return;

    // coefficients pre-scaled by log2(e): exp(P(c,z)) == exp2(P(c*log2e, z))
    const float a0 = pa[0] * LOG2E, a1 = pa[1] * LOG2E, a2 = pa[2] * LOG2E,
                a3 = pa[3] * LOG2E, a4 = pa[4] * LOG2E;
    const float b0 = pb[0] * LOG2E, b1 = pb[1] * LOG2E, b2 = pb[2] * LOG2E,
                b3 = pb[3] * LOG2E, b4 = pb[4] * LOG2E;

    const float zs  = zs_arr[bid];
    const float zs2 = zs * zs;
    const float zs4 = zs2 * zs2;
    const float fzs = (1.0f - zs4) *
        exp2_raw(zs * poly_h(a0, a1, a2, a3, a4, zs, zs2, zs4));

    const float hL = (1.0f - 2.0f * EPSF) / (float)(NU_L - 1);
    const float hV = (1.0f - 2.0f * EPSF) / (float)(NU_V - 1);

    float Lre = 0.0f, Lim = 0.0f, Vre = 0.0f, Vim = 0.0f;

    // two isomorphic scalar chains per iteration -> SLP into v_pk_fma_f32
    for (int k = tid; k < NU_L; k += 512) {
        point_L(k,       zs, zs4, fzs, hL, a0,a1,a2,a3,a4, b0,b1,b2,b3,b4, Lre, Lim);
        point_L(k + 256, zs, zs4, fzs, hL, a0,a1,a2,a3,a4, b0,b1,b2,b3,b4, Lre, Lim);
    }
    for (int k = tid; k < NU_V; k += 512) {
        point_V(k,       zs, zs4, fzs, hV, a0,a1,a2,a3,a4, b0,b1,b2,b3,b4, Vre, Vim);
        point_V(k + 256, zs, zs4, fzs, hV, a0,a1,a2,a3,a4, b0,b1,b2,b3,b4, Vre, Vim);
    }

    // ---------------- block reduction (4 waves of 64) ----------------
    for (int off = 32; off > 0; off >>= 1) {
        Lre += __shfl_down(Lre, off);
        Lim += __shfl_down(Lim, off);
        Vre += __shfl_down(Vre, off);
        Vim += __shfl_down(Vim, off);
    }
    __shared__ float4 wsum[4];
    const int lane = tid & 63;
    const int wid  = tid >> 6;
    if (lane == 0) wsum[wid] = make_float4(Lre, Lim, Vre, Vim);
    __syncthreads();
    if (tid == 0) {
        float4 t = wsum[0];
        t.x += wsum[1].x + wsum[2].x + wsum[3].x;
        t.y += wsum[1].y + wsum[2].y + wsum[3].y;
        t.z += wsum[1].z + wsum[2].z + wsum[3].z;
        t.w += wsum[1].w + wsum[2].w + wsum[3].w;

        const float twopi = 2.0f * PIF;
        const float sL = (2.0f / PIF) * zs * hL;   // (2/pi) * zs * du
        const float sV = twopi * zs * hV;          // 2*pi * zs * du
        out[0 * B + bid] = t.x * sL;
        out[1 * B + bid] = t.y * sL;
        out[2 * B + bid] = t.z * sV - twopi / zs;  // minus V_disc (real)
        out[3 * B + bid] = t.w * sV;
    }
}

extern "C" void kernel_launch(void* const* d_in, const int* in_sizes, int n_in,
                              void* d_out, int out_size, void* d_ws, size_t ws_size,
                              hipStream_t stream) {
    const float* a  = (const float*)d_in[0];
    const float* b  = (const float*)d_in[1];
    const float* zs = (const float*)d_in[2];
    float* out = (float*)d_out;
    const int B = in_sizes[2];
    adsbh_kernel<<<B, 256, 0, stream>>>(a, b, zs, out, B);
}

// Round 4
// 95.956 us; speedup vs baseline: 1.7671x; 1.0705x over previous
//
#include <hip/hip_runtime.h>
#include <math.h>

#define NU_L 2000
#define NU_V 1500
#define EPSF 1e-6f
#define EPS2 1e-12f
#define PIF   3.14159265358979323846f
#define LOG2E 1.44269504088896340736f

typedef float v2f __attribute__((ext_vector_type(2)));

__device__ __forceinline__ float exp2s(float x) {
#if __has_builtin(__builtin_amdgcn_exp2f)
    return __builtin_amdgcn_exp2f(x);
#else
    return exp2f(x);
#endif
}
__device__ __forceinline__ v2f exp2_2(v2f x){ v2f r; r.x=exp2s(x.x); r.y=exp2s(x.y); return r; }
__device__ __forceinline__ v2f rsq_2(v2f x){ v2f r; r.x=__builtin_amdgcn_rsqf(x.x); r.y=__builtin_amdgcn_rsqf(x.y); return r; }
__device__ __forceinline__ v2f sqrt_2(v2f x){ v2f r; r.x=__builtin_amdgcn_sqrtf(x.x); r.y=__builtin_amdgcn_sqrtf(x.y); return r; }
__device__ __forceinline__ v2f rcp_2(v2f x){ v2f r; r.x=__builtin_amdgcn_rcpf(x.x); r.y=__builtin_amdgcn_rcpf(x.y); return r; }
__device__ __forceinline__ v2f fma2(v2f a, v2f b, v2f c){
#if __has_builtin(__builtin_elementwise_fma)
    return __builtin_elementwise_fma(a,b,c);
#else
    v2f r; r.x=fmaf(a.x,b.x,c.x); r.y=fmaf(a.y,b.y,c.y); return r;
#endif
}
__device__ __forceinline__ v2f sv(float s){ v2f r = {s, s}; return r; }
__device__ __forceinline__ v2f abs2(v2f x){ v2f r; r.x=__builtin_fabsf(x.x); r.y=__builtin_fabsf(x.y); return r; }

__global__ __launch_bounds__(256) void adsbh_kernel(
    const float* __restrict__ pa, const float* __restrict__ pb,
    const float* __restrict__ zs_arr, float* __restrict__ out, int B)
{
    const int bid = blockIdx.x;
    const int tid = threadIdx.x & 255;   // range hint [0,255] for compile-time mask elision

    // coefficient sets (pre-scaled by log2 e):
    //   a* : Pa            (for f)
    //   h* : 0.5*Pb        (for sqrt(g) in L)
    //   c* : 0.5*(Pa+Pb)   (for sqrt(f*g) in V)
    const float a0 = pa[0]*LOG2E, a1 = pa[1]*LOG2E, a2 = pa[2]*LOG2E,
                a3 = pa[3]*LOG2E, a4 = pa[4]*LOG2E;
    const float h0 = 0.5f*pb[0]*LOG2E, h1 = 0.5f*pb[1]*LOG2E, h2 = 0.5f*pb[2]*LOG2E,
                h3 = 0.5f*pb[3]*LOG2E, h4 = 0.5f*pb[4]*LOG2E;
    const float c0 = 0.5f*a0 + h0, c1 = 0.5f*a1 + h1, c2 = 0.5f*a2 + h2,
                c3 = 0.5f*a3 + h3, c4 = 0.5f*a4 + h4;

    const float zs  = zs_arr[bid];
    const float zs2 = zs * zs;
    const float zs4 = zs2 * zs2;
    const float Hs  = fmaf(a4, zs4, fmaf(zs2, fmaf(a3, zs, a2), fmaf(a1, zs, a0)));
    const float fzs = (1.0f - zs4) * exp2s(zs * Hs);

    const float hL = (1.0f - 2.0f * EPSF) / (float)(NU_L - 1);
    const float hV = (1.0f - 2.0f * EPSF) / (float)(NU_V - 1);
    const float tf = (float)tid;

    // P(z) = z * (c0 + c1 z + c2 z^2 + c3 z^3 + c4 z^4), Estrin
    auto poly2 = [&](v2f z, v2f z2, v2f z4,
                     float q0, float q1, float q2, float q3, float q4) -> v2f {
        v2f p01 = fma2(sv(q1), z, sv(q0));
        v2f p23 = fma2(sv(q3), z, sv(q2));
        v2f h   = fma2(z2, p23, p01);
        h = fma2(sv(q4), z4, h);
        return z * h;
    };

    // sx / csqrt(nx + i ny), principal branch, sx real > 0.
    // Reflected half-angle: work in first quadrant (no cancellation), restore signs.
    auto icsq2 = [&](v2f nx, v2f ny, v2f sx, v2f& wre, v2f& wim) {
        v2f ax = abs2(nx), ay = abs2(ny);
        v2f r2 = fma2(nx, nx, ny*ny);
        v2f ir = rsq_2(r2);
        v2f r  = r2 * ir;                 // |n|
        v2f px = ax + r;                  // in [r, 2r] — never cancels
        v2f q2 = fma2(px, px, ay*ay);
        v2f s  = rsq_2(q2 * r) * sx;      // sx/( |p| * sqrt|n| )
        v2f cc = px * s, dd = ay * s;
        wre.x = (nx.x < 0.0f) ? dd.x : cc.x;
        wre.y = (nx.y < 0.0f) ? dd.y : cc.y;
        float t0 = (nx.x < 0.0f) ? cc.x : dd.x;
        float t1 = (nx.y < 0.0f) ? cc.y : dd.y;
        wim.x = -__builtin_copysignf(t0, ny.x);
        wim.y = -__builtin_copysignf(t1, ny.y);
    };

    // L integrand (unweighted): sqrt(g)/csqrt(denom)
    auto evalL = [&](v2f u, v2f& re2, v2f& im2) {
        v2f z = u * zs;
        v2f z2 = z*z, z4 = z2*z2;
        v2f omz4 = sv(1.0f) - z4;
        v2f Pa = poly2(z, z2, z4, a0,a1,a2,a3,a4);
        v2f Ph = poly2(z, z2, z4, h0,h1,h2,h3,h4);
        v2f fz = omz4 * exp2_2(Pa);
        v2f sg = exp2_2(Ph) * rsq_2(omz4);           // sqrt(g(z))
        v2f A  = fz * zs4;
        v2f dx = fma2(z4, sv(fzs), sv(EPSF));
        v2f D  = fma2(dx, dx, sv(EPS2));
        v2f nx = fma2(sv(EPSF), D, fma2(A, dx, -D)); // A dx - D(1-eps)
        v2f ny = (D - A) * EPSF;
        v2f sD = sqrt_2(D);
        v2f wre, wim;
        icsq2(nx, ny, sD, wre, wim);
        re2 = sg * wre;
        im2 = sg * wim;
    };

    // V integrand (unweighted): (F/csqrt(inner) - 1)/(z^2 + eps(1+i))
    auto evalV = [&](v2f u, v2f& re2, v2f& im2) {
        v2f z = u * zs;
        v2f z2 = z*z, z4 = z2*z2;
        v2f omz4 = sv(1.0f) - z4;
        v2f Pa = poly2(z, z2, z4, a0,a1,a2,a3,a4);
        v2f Pc = poly2(z, z2, z4, c0,c1,c2,c3,c4);
        v2f fz = omz4 * exp2_2(Pa);
        v2f F  = exp2_2(Pc);                          // sqrt(f*g), (1-z^4) cancels
        v2f Bv = z4 * fzs;
        v2f dx = fma2(sv(zs4), fz, sv(EPSF));
        v2f D  = fma2(dx, dx, sv(EPS2));
        v2f nx = fma2(sv(EPSF), D, fma2(-Bv, dx, D)); // D(1+eps) - Bv dx
        v2f ny = (Bv + D) * EPSF;
        v2f sF = sqrt_2(D) * F;
        v2f wre, wim;
        icsq2(nx, ny, sF, wre, wim);
        v2f tre = wre - sv(1.0f);
        v2f tim = wim;
        v2f ddx = z2 + sv(EPSF);
        v2f idn = rcp_2(fma2(ddx, ddx, sv(EPS2)));
        re2 = fma2(tre, ddx, tim * EPSF) * idn;
        im2 = fma2(tim, ddx, tre * (-EPSF)) * idn;
    };

    v2f aLre = sv(0.0f), aLim = sv(0.0f), aVre = sv(0.0f), aVim = sv(0.0f);

    auto doL = [&](float K0, float K1, bool chk1) {
        float k0 = tf + K0, k1 = tf + K1;
        v2f u; u.x = fmaf(k0, hL, EPSF); u.y = fmaf(k1, hL, EPSF);
        float m1 = 1.0f;
        if (chk1) { bool act = (k1 <= (float)(NU_L-1)); m1 = act ? 1.0f : 0.0f; u.y = act ? u.y : 0.5f; }
        v2f re2, im2; evalL(u, re2, im2);
        if (chk1) { re2.y *= m1; im2.y *= m1; }
        aLre += re2; aLim += im2;
    };
    auto doV = [&](float K0, float K1, bool chk1) {
        float k0 = tf + K0, k1 = tf + K1;
        v2f u; u.x = fmaf(k0, hV, EPSF); u.y = fmaf(k1, hV, EPSF);
        float m1 = 1.0f;
        if (chk1) { bool act = (k1 <= (float)(NU_V-1)); m1 = act ? 1.0f : 0.0f; u.y = act ? u.y : 0.5f; }
        v2f re2, im2; evalV(u, re2, im2);
        if (chk1) { re2.y *= m1; im2.y *= m1; }
        aVre += re2; aVim += im2;
    };

    // L: 8 points/thread (2000 = 256*7 + 208); only last component can be OOB
    doL(0.0f,    256.0f,  false);
    doL(512.0f,  768.0f,  false);
    doL(1024.0f, 1280.0f, false);
    doL(1536.0f, 1792.0f, true);
    // V: 6 points/thread (1500 = 256*5 + 220)
    doV(0.0f,    256.0f,  false);
    doV(512.0f,  768.0f,  false);
    doV(1024.0f, 1280.0f, true);

    float Lre = aLre.x + aLre.y, Lim = aLim.x + aLim.y;
    float Vre = aVre.x + aVre.y, Vim = aVim.x + aVim.y;

    // ---------------- block reduction (4 waves of 64) ----------------
    for (int off = 32; off > 0; off >>= 1) {
        Lre += __shfl_down(Lre, off);
        Lim += __shfl_down(Lim, off);
        Vre += __shfl_down(Vre, off);
        Vim += __shfl_down(Vim, off);
    }
    __shared__ float4 wsum[4];
    __shared__ float4 corr;   // 0.5*(endpoint integrands): L.re, L.im, V.re, V.im
    const int lane = tid & 63;
    const int wid  = tid >> 6;
    if (lane == 0) wsum[wid] = make_float4(Lre, Lim, Vre, Vim);
    // trapezoid endpoint half-weight fixups (w=1 was used everywhere above)
    if (tid == 0) {
        v2f u; u.x = EPSF; u.y = fmaf((float)(NU_L-1), hL, EPSF);
        v2f re2, im2; evalL(u, re2, im2);
        corr.x = 0.5f * (re2.x + re2.y);
        corr.y = 0.5f * (im2.x + im2.y);
    }
    if (tid == 64) {
        v2f u; u.x = EPSF; u.y = fmaf((float)(NU_V-1), hV, EPSF);
        v2f re2, im2; evalV(u, re2, im2);
        corr.z = 0.5f * (re2.x + re2.y);
        corr.w = 0.5f * (im2.x + im2.y);
    }
    __syncthreads();
    if (tid == 0) {
        float4 t = wsum[0];
        t.x += wsum[1].x + wsum[2].x + wsum[3].x;
        t.y += wsum[1].y + wsum[2].y + wsum[3].y;
        t.z += wsum[1].z + wsum[2].z + wsum[3].z;
        t.w += wsum[1].w + wsum[2].w + wsum[3].w;
        t.x -= corr.x;  t.y -= corr.y;
        t.z -= corr.z;  t.w -= corr.w;

        const float twopi = 2.0f * PIF;
        const float sL = (2.0f / PIF) * zs * hL;   // (2/pi) * zs * du
        const float sV = twopi * zs * hV;          // 2*pi * zs * du
        out[0 * B + bid] = t.x * sL;
        out[1 * B + bid] = t.y * sL;
        out[2 * B + bid] = t.z * sV - twopi / zs;  // minus V_disc (real)
        out[3 * B + bid] = t.w * sV;
    }
}

extern "C" void kernel_launch(void* const* d_in, const int* in_sizes, int n_in,
                              void* d_out, int out_size, void* d_ws, size_t ws_size,
                              hipStream_t stream) {
    const float* a  = (const float*)d_in[0];
    const float* b  = (const float*)d_in[1];
    const float* zs = (const float*)d_in[2];
    float* out = (float*)d_out;
    const int B = in_sizes[2];
    adsbh_kernel<<<B, 256, 0, stream>>>(a, b, zs, out, B);
}

// Round 5
// 94.617 us; speedup vs baseline: 1.7921x; 1.0141x over previous
//
#include <hip/hip_runtime.h>
#include <math.h>

#define NU_L 2000
#define NU_V 1500
#define EPSF 1e-6f
#define EPS2 1e-12f
#define PIF   3.14159265358979323846f
#define LOG2E 1.44269504088896340736f

typedef float v2f __attribute__((ext_vector_type(2)));

// ---- scalar hardware transcendentals (no packed variants exist) ----
__device__ __forceinline__ float exp2s(float x) { return __builtin_amdgcn_exp2f(x); }
__device__ __forceinline__ v2f exp2_2(v2f x){ v2f r; r.x=exp2s(x.x); r.y=exp2s(x.y); return r; }
__device__ __forceinline__ v2f rsq_2(v2f x){ v2f r; r.x=__builtin_amdgcn_rsqf(x.x); r.y=__builtin_amdgcn_rsqf(x.y); return r; }
__device__ __forceinline__ v2f sqrt_2(v2f x){ v2f r; r.x=__builtin_amdgcn_sqrtf(x.x); r.y=__builtin_amdgcn_sqrtf(x.y); return r; }
__device__ __forceinline__ v2f rcp_2(v2f x){ v2f r; r.x=__builtin_amdgcn_rcpf(x.x); r.y=__builtin_amdgcn_rcpf(x.y); return r; }

// ---- fully-vector full-rate helpers (keep <2 x float> IR intact) ----
__device__ __forceinline__ v2f fma2(v2f a, v2f b, v2f c){
#if __has_builtin(__builtin_elementwise_fma)
    return __builtin_elementwise_fma(a,b,c);
#else
    return a*b + c;   // -ffp-contract=fast fuses, stays vector
#endif
}
__device__ __forceinline__ v2f abs2(v2f x){
#if __has_builtin(__builtin_elementwise_abs)
    return __builtin_elementwise_abs(x);
#else
    v2f r; r.x=__builtin_fabsf(x.x); r.y=__builtin_fabsf(x.y); return r;
#endif
}
__device__ __forceinline__ v2f cpsgn2(v2f m, v2f s){
#if __has_builtin(__builtin_elementwise_copysign)
    return __builtin_elementwise_copysign(m, s);
#else
    v2f r; r.x=__builtin_copysignf(m.x,s.x); r.y=__builtin_copysignf(m.y,s.y); return r;
#endif
}
__device__ __forceinline__ v2f sv(float s){ v2f r = {s, s}; return r; }

__global__ __launch_bounds__(256) void adsbh_kernel(
    const float* __restrict__ pa, const float* __restrict__ pb,
    const float* __restrict__ zs_arr, float* __restrict__ out, int B)
{
    const int bid = blockIdx.x;
    const int tid = threadIdx.x & 255;   // range hint

    // coefficient sets (pre-scaled by log2 e):
    //   a*: Pa (for f);  h*: Pb/2 (sqrt(g) in L);  c*: (Pa+Pb)/2 (sqrt(fg) in V)
    const float a0 = pa[0]*LOG2E, a1 = pa[1]*LOG2E, a2 = pa[2]*LOG2E,
                a3 = pa[3]*LOG2E, a4 = pa[4]*LOG2E;
    const float h0 = 0.5f*pb[0]*LOG2E, h1 = 0.5f*pb[1]*LOG2E, h2 = 0.5f*pb[2]*LOG2E,
                h3 = 0.5f*pb[3]*LOG2E, h4 = 0.5f*pb[4]*LOG2E;
    const float c0 = 0.5f*a0 + h0, c1 = 0.5f*a1 + h1, c2 = 0.5f*a2 + h2,
                c3 = 0.5f*a3 + h3, c4 = 0.5f*a4 + h4;

    const float zs  = zs_arr[bid];
    const float zs2 = zs * zs;
    const float zs4 = zs2 * zs2;
    const float Hs  = fmaf(a4, zs4, fmaf(zs2, fmaf(a3, zs, a2), fmaf(a1, zs, a0)));
    const float fzs = (1.0f - zs4) * exp2s(zs * Hs);

    const float hL = (1.0f - 2.0f * EPSF) / (float)(NU_L - 1);
    const float hV = (1.0f - 2.0f * EPSF) / (float)(NU_V - 1);
    const float tf = (float)tid;

    // P(z) = z * (q0 + q1 z + q2 z^2 + q3 z^3 + q4 z^4), Estrin, all vector
    auto poly2 = [&](v2f z, v2f z2, v2f z4,
                     float q0, float q1, float q2, float q3, float q4) -> v2f {
        v2f p01 = fma2(sv(q1), z, sv(q0));
        v2f p23 = fma2(sv(q3), z, sv(q2));
        v2f h   = fma2(z2, p23, p01);
        h = fma2(sv(q4), z4, h);
        return z * h;
    };

    // sx / csqrt(nx + i ny) = (wre, -timp): branch-free, all-vector.
    // Half-angle in first quadrant (px = |nx|+|n| never cancels), signs via
    // arithmetic blend m = 0.5 - copysign(0.5, nx) and timp = copysign(t, ny).
    auto icsq2 = [&](v2f nx, v2f ny, v2f sx, v2f& wre, v2f& timp) {
        v2f ax = abs2(nx), ay = abs2(ny);
        v2f r2 = fma2(nx, nx, ny*ny);
        v2f ir = rsq_2(r2);
        v2f r  = r2 * ir;                  // |n|
        v2f px = ax + r;
        v2f q2 = fma2(px, px, ay*ay);
        v2f s  = rsq_2(q2 * r) * sx;       // sx / (|p| sqrt|n|)
        v2f cc = px * s, dd = ay * s;
        v2f m  = sv(0.5f) - cpsgn2(sv(0.5f), nx);   // 0 (nx>=0) or 1 (nx<0)
        wre    = fma2(dd - cc, m, cc);
        v2f t  = (cc + dd) - wre;          // the other candidate
        timp   = cpsgn2(t, ny);            // actual wim = -timp
    };

    // L integrand (unweighted): re2 = Re, liP = -Im
    auto evalL = [&](v2f u, v2f& re2, v2f& liP) {
        v2f z = u * sv(zs);
        v2f z2 = z*z, z4 = z2*z2;
        v2f omz4 = sv(1.0f) - z4;
        v2f Pa = poly2(z, z2, z4, a0,a1,a2,a3,a4);
        v2f Ph = poly2(z, z2, z4, h0,h1,h2,h3,h4);
        v2f fz = omz4 * exp2_2(Pa);
        v2f sg = exp2_2(Ph) * rsq_2(omz4);            // sqrt(g)
        v2f A  = fz * sv(zs4);
        v2f dx = fma2(z4, sv(fzs), sv(EPSF));
        v2f D  = fma2(dx, dx, sv(EPS2));
        v2f nx = fma2(sv(EPSF), D, fma2(A, dx, -D));  // A dx - D(1-eps)
        v2f ny = (D - A) * sv(EPSF);
        v2f sD = sqrt_2(D);
        v2f wre, timp;
        icsq2(nx, ny, sD, wre, timp);
        re2 = sg * wre;
        liP = sg * timp;
    };

    // V integrand (unweighted): re2 = Re, viP = -Im
    auto evalV = [&](v2f u, v2f& re2, v2f& viP) {
        v2f z = u * sv(zs);
        v2f z2 = z*z, z4 = z2*z2;
        v2f omz4 = sv(1.0f) - z4;
        v2f Pa = poly2(z, z2, z4, a0,a1,a2,a3,a4);
        v2f Pc = poly2(z, z2, z4, c0,c1,c2,c3,c4);
        v2f fz = omz4 * exp2_2(Pa);
        v2f F  = exp2_2(Pc);                          // sqrt(f g)
        v2f Bv = z4 * sv(fzs);
        v2f dx = fma2(sv(zs4), fz, sv(EPSF));
        v2f D  = fma2(dx, dx, sv(EPS2));
        v2f nx = fma2(sv(EPSF), D, fma2(-Bv, dx, D)); // D(1+eps) - Bv dx
        v2f ny = (Bv + D) * sv(EPSF);
        v2f sx = sqrt_2(D) * F;
        v2f wre, timp;
        icsq2(nx, ny, sx, wre, timp);
        v2f tre = wre - sv(1.0f);                     // tim = -timp
        v2f ddx = z2 + sv(EPSF);
        v2f idn = rcp_2(fma2(ddx, ddx, sv(EPS2)));
        re2 = fma2(tre, ddx, timp * sv(-EPSF)) * idn;       // (tre ddx + tim eps)/|d|^2
        viP = fma2(timp, ddx, tre * sv(EPSF)) * idn;        // -Im
    };

    v2f aLre = sv(0.0f), aLiP = sv(0.0f), aVre = sv(0.0f), aViP = sv(0.0f);
    v2f re2, imP;

    // ---- L: 4 bundles (2000 = 7*256 + 208; only lane .y of last can be OOB)
    {
        v2f u;
        u = fma2(sv(tf) + (v2f){0.0f, 256.0f},    sv(hL), sv(EPSF));
        evalL(u, re2, imP); aLre += re2; aLiP += imP;
        u = fma2(sv(tf) + (v2f){512.0f, 768.0f},  sv(hL), sv(EPSF));
        evalL(u, re2, imP); aLre += re2; aLiP += imP;
        u = fma2(sv(tf) + (v2f){1024.0f, 1280.0f},sv(hL), sv(EPSF));
        evalL(u, re2, imP); aLre += re2; aLiP += imP;
        bool act = (tid <= 207);                      // tid+1792 <= 1999
        u = fma2(sv(tf) + (v2f){1536.0f, 1792.0f},sv(hL), sv(EPSF));
        u.y = act ? u.y : 0.25f;
        v2f mk = {1.0f, act ? 1.0f : 0.0f};
        evalL(u, re2, imP);
        aLre = fma2(re2, mk, aLre); aLiP = fma2(imP, mk, aLiP);
    }
    // ---- V: 3 bundles (1500 = 5*256 + 220)
    {
        v2f u;
        u = fma2(sv(tf) + (v2f){0.0f, 256.0f},    sv(hV), sv(EPSF));
        evalV(u, re2, imP); aVre += re2; aViP += imP;
        u = fma2(sv(tf) + (v2f){512.0f, 768.0f},  sv(hV), sv(EPSF));
        evalV(u, re2, imP); aVre += re2; aViP += imP;
        bool act = (tid <= 219);                      // tid+1280 <= 1499
        u = fma2(sv(tf) + (v2f){1024.0f, 1280.0f},sv(hV), sv(EPSF));
        u.y = act ? u.y : 0.25f;
        v2f mk = {1.0f, act ? 1.0f : 0.0f};
        evalV(u, re2, imP);
        aVre = fma2(re2, mk, aVre); aViP = fma2(imP, mk, aViP);
    }

    float Lre = aLre.x + aLre.y, LiP = aLiP.x + aLiP.y;
    float Vre = aVre.x + aVre.y, ViP = aViP.x + aViP.y;

    // ---------------- block reduction (4 waves of 64) ----------------
    for (int off = 32; off > 0; off >>= 1) {
        Lre += __shfl_down(Lre, off);
        LiP += __shfl_down(LiP, off);
        Vre += __shfl_down(Vre, off);
        ViP += __shfl_down(ViP, off);
    }
    __shared__ float4 wsum[4];
    __shared__ float4 corr;   // 0.5*(endpoint sums): Lre, LiP, Vre, ViP
    const int lane = tid & 63;
    const int wid  = tid >> 6;
    if (lane == 0) wsum[wid] = make_float4(Lre, LiP, Vre, ViP);
    // trapezoid endpoint half-weight fixups (w=1 was used everywhere above)
    if (tid == 0) {
        v2f u; u.x = EPSF; u.y = fmaf((float)(NU_L-1), hL, EPSF);
        v2f r2e, iPe; evalL(u, r2e, iPe);
        corr.x = 0.5f * (r2e.x + r2e.y);
        corr.y = 0.5f * (iPe.x + iPe.y);
    }
    if (tid == 64) {
        v2f u; u.x = EPSF; u.y = fmaf((float)(NU_V-1), hV, EPSF);
        v2f r2e, iPe; evalV(u, r2e, iPe);
        corr.z = 0.5f * (r2e.x + r2e.y);
        corr.w = 0.5f * (iPe.x + iPe.y);
    }
    __syncthreads();
    if (tid == 0) {
        float4 t = wsum[0];
        t.x += wsum[1].x + wsum[2].x + wsum[3].x;
        t.y += wsum[1].y + wsum[2].y + wsum[3].y;
        t.z += wsum[1].z + wsum[2].z + wsum[3].z;
        t.w += wsum[1].w + wsum[2].w + wsum[3].w;
        t.x -= corr.x;  t.y -= corr.y;
        t.z -= corr.z;  t.w -= corr.w;

        const float twopi = 2.0f * PIF;
        const float sL = (2.0f / PIF) * zs * hL;
        const float sV = twopi * zs * hV;
        out[0 * B + bid] =  t.x * sL;
        out[1 * B + bid] = -t.y * sL;                 // Im = -(P sum)
        out[2 * B + bid] =  t.z * sV - twopi / zs;
        out[3 * B + bid] = -t.w * sV;
    }
}

extern "C" void kernel_launch(void* const* d_in, const int* in_sizes, int n_in,
                              void* d_out, int out_size, void* d_ws, size_t ws_size,
                              hipStream_t stream) {
    const float* a  = (const float*)d_in[0];
    const float* b  = (const float*)d_in[1];
    const float* zs = (const float*)d_in[2];
    float* out = (float*)d_out;
    const int B = in_sizes[2];
    adsbh_kernel<<<B, 256, 0, stream>>>(a, b, zs, out, B);
}

// Round 7
// 77.648 us; speedup vs baseline: 2.1837x; 1.2185x over previous
//
#include <hip/hip_runtime.h>
#include <math.h>

#define NU_L 2000
#define NU_V 1500
#define EPSF 1e-6f
#define EPS2 1e-12f
#define PIF   3.14159265358979323846f
#define LOG2E 1.44269504088896340736f

__device__ __forceinline__ float exp2s(float x) { return __builtin_amdgcn_exp2f(x); }
__device__ __forceinline__ float rsqs(float x)  { return __builtin_amdgcn_rsqf(x); }
__device__ __forceinline__ float rcps(float x)  { return __builtin_amdgcn_rcpf(x); }
__device__ __forceinline__ float sqrts(float x) { return __builtin_amdgcn_sqrtf(x); }

__global__ __launch_bounds__(256) void adsbh_kernel(
    const float* __restrict__ pa, const float* __restrict__ pb,
    const float* __restrict__ zs_arr, float* __restrict__ out, int B)
{
    const int bid = blockIdx.x;
    const int tid = threadIdx.x & 255;

    // coefficient sets (pre-scaled by log2 e):
    //   a*: Pa (for f);  h*: Pb/2 (sqrt(g) in L);  c*: (Pa+Pb)/2 (sqrt(fg) in V)
    const float a0 = pa[0]*LOG2E, a1 = pa[1]*LOG2E, a2 = pa[2]*LOG2E,
                a3 = pa[3]*LOG2E, a4 = pa[4]*LOG2E;
    const float h0 = 0.5f*pb[0]*LOG2E, h1 = 0.5f*pb[1]*LOG2E, h2 = 0.5f*pb[2]*LOG2E,
                h3 = 0.5f*pb[3]*LOG2E, h4 = 0.5f*pb[4]*LOG2E;
    const float c0 = 0.5f*a0 + h0, c1 = 0.5f*a1 + h1, c2 = 0.5f*a2 + h2,
                c3 = 0.5f*a3 + h3, c4 = 0.5f*a4 + h4;

    const float zs  = zs_arr[bid];
    const float zs2 = zs * zs;
    const float zs4 = zs2 * zs2;
    const float Hs  = fmaf(a4, zs4, fmaf(zs2, fmaf(a3, zs, a2), fmaf(a1, zs, a0)));
    const float fzs = (1.0f - zs4) * exp2s(zs * Hs);

    const float hL = (1.0f - 2.0f * EPSF) / (float)(NU_L - 1);
    const float hV = (1.0f - 2.0f * EPSF) / (float)(NU_V - 1);

    float Lre = 0.0f, LiP = 0.0f, Vre = 0.0f, ViP = 0.0f;  // *iP = -Im

    // ---- L integrand eval, weight w (in units of hL); w=0 => masked ----
    // integrand = sqrt(g)/csqrt(denom); denom = num/D, D>0 real.
    // Reflected half-angle (P=|nx|+r, cancellation-free for all quadrants):
    //   scale = exp2(Ph-0.5)*sqrt(D/(omz4*P*r^2))
    //   nx>=0: (Re,-Im) = (P, sgn(ny)|ny|)*scale ; nx<0: (|ny|, sgn(ny)P)*scale
    auto evalL = [&](float u, float w) {
        float z = zs*u, z2 = z*z, z4 = z2*z2;
        float omz4 = 1.0f - z4;
        float pA  = fmaf(a1, z, a0), pA2 = fmaf(a3, z, a2);
        float hA  = fmaf(z2, pA2, pA); hA = fmaf(a4, z4, hA);
        float Pa  = z * hA;
        float pH  = fmaf(h1, z, h0), pH2 = fmaf(h3, z, h2);
        float hH  = fmaf(z2, pH2, pH); hH = fmaf(h4, z4, hH);
        float PhM = fmaf(z, hH, -0.5f);          // Ph - 0.5 (folds sqrt(1/2))
        float Ea  = exp2s(Pa);                   // T1
        float Eh  = exp2s(PhM);                  // T2
        float fz  = omz4 * Ea;
        float A   = zs4 * fz;
        float dx  = fmaf(z4, fzs, EPSF);
        float D   = fmaf(dx, dx, EPS2);
        float t1  = fmaf(A, dx, -D);
        float nx  = fmaf(EPSF, D, t1);           // A*dx - D(1-eps)
        float ny  = EPSF * (D - A);
        float ny2 = ny * ny;
        float r2  = fmaf(nx, nx, ny2);
        float ir  = rsqs(r2);                    // T3
        float r   = r2 * ir;
        float P   = fabsf(nx) + r;
        float W   = omz4 * (P * r2);
        float iW  = rcps(W);                     // T4
        float S   = sqrts(D * iW);               // T5
        float SS  = (S * Eh) * w;
        float cA  = P * SS, cB = fabsf(ny) * SS;
        bool  neg = nx < 0.0f;
        float re  = neg ? cB : cA;
        float ti  = neg ? cA : cB;
        Lre += re;
        LiP += copysignf(ti, ny);
    };

    // ---- V integrand eval: term = F/csqrt(inner) - 1, then /(z^2+eps(1+i))
    auto evalV = [&](float u, float w) {
        float z = zs*u, z2 = z*z, z4 = z2*z2;
        float omz4 = 1.0f - z4;
        float pA  = fmaf(a1, z, a0), pA2 = fmaf(a3, z, a2);
        float hA  = fmaf(z2, pA2, pA); hA = fmaf(a4, z4, hA);
        float Pa  = z * hA;
        float pC  = fmaf(c1, z, c0), pC2 = fmaf(c3, z, c2);
        float hC  = fmaf(z2, pC2, pC); hC = fmaf(c4, z4, hC);
        float PcM = fmaf(z, hC, -0.5f);          // Pc - 0.5 (folds sqrt(1/2))
        float Ea  = exp2s(Pa);                   // T1
        float Fs  = exp2s(PcM);                  // T2
        float fz  = omz4 * Ea;
        float Bv  = z4 * fzs;
        float dx  = fmaf(zs4, fz, EPSF);
        float D   = fmaf(dx, dx, EPS2);
        float t1  = fmaf(Bv, dx, -D);
        float nx  = fmaf(EPSF, D, -t1);          // D(1+eps) - Bv*dx
        float ny  = EPSF * (Bv + D);
        float ny2 = ny * ny;
        float r2  = fmaf(nx, nx, ny2);
        float ir  = rsqs(r2);                    // T3
        float r   = r2 * ir;
        float P   = fabsf(nx) + r;
        float W   = P * r2;
        float iW  = rcps(W);                     // T4
        float S   = sqrts(D * iW);               // T5
        float SS  = S * Fs;
        float cA  = P * SS, cB = fabsf(ny) * SS;
        bool  neg = nx < 0.0f;
        float wre = neg ? cB : cA;
        float wti = neg ? cA : cB;
        float tre = wre - 1.0f;
        float tiP = copysignf(wti, ny);          // -Im(term numerator part)
        float ddx = z2 + EPSF;
        float idn = rcps(fmaf(ddx, ddx, EPS2));  // T6
        float re  = fmaf(tre, ddx, -(tiP * EPSF)) * idn;
        float iP  = fmaf(tiP, ddx,   tre * EPSF) * idn;
        Vre = fmaf(w, re, Vre);
        ViP = fmaf(w, iP, ViP);
    };

    const float tf = (float)tid;

    // ======== L: nodes = {0,4,...,1788} coarse + {1792..1999} fine = 656 ========
    // weights (h units): idx0=2, coarse interior=4, idx448(k=1792)=2.5,
    //                    fine interior=1, idx655(k=1999)=0.5
    {   // round 0: idx = tid in [0,255] -> all coarse
        float w = (tid == 0) ? 2.0f : 4.0f;
        evalL(fmaf(4.0f * tf, hL, EPSF), w);
    }
    {   // round 1: idx = tid+256 in [256,511] -> coarse if idx<448
        int idx = tid + 256;
        bool c = idx < 448;
        float kf = c ? (float)(4 * idx) : (float)(idx + 1344);
        float w  = c ? 4.0f : 1.0f;
        if (idx == 448) w = 2.5f;
        evalL(fmaf(kf, hL, EPSF), w);
    }
    {   // round 2: idx = tid+512 in [512,767] -> fine; inactive past 655
        int idx = tid + 512;
        bool ina = idx > 655;
        float w = ina ? 0.0f : ((idx == 655) ? 0.5f : 1.0f);
        float u = ina ? 0.5f : fmaf((float)(idx + 1344), hL, EPSF);
        evalL(u, w);
    }

    // ======== V: {0..255} fine + {256,260,...,1288} coarse + {1292..1499} fine = 723
    // weights: idx0=0.5, fine=1, idx256(k=256)=2.5, coarse=4, idx515(k=1292)=2.5,
    //          idx722(k=1499)=0.5
    {   // round 0: idx = tid -> fine start
        float w = (tid == 0) ? 0.5f : 1.0f;
        evalV(fmaf(tf, hV, EPSF), w);
    }
    {   // round 1: idx = tid+256 in [256,511] -> all coarse, k = 4*idx-768
        float kf = fmaf(4.0f, tf, 256.0f);       // 4*(tid+256)-768
        float w  = (tid == 0) ? 2.5f : 4.0f;
        evalV(fmaf(kf, hV, EPSF), w);
    }
    {   // round 2: idx = tid+512 in [512,767]: coarse <515, fine 515..722, inact >722
        int idx = tid + 512;
        bool c   = idx < 515;
        bool ina = idx > 722;
        float kf = c ? (float)(4 * idx - 768) : (float)(idx + 777);
        float w  = c ? 4.0f : 1.0f;
        if (idx == 515) w = 2.5f;
        if (idx == 722) w = 0.5f;
        if (ina) w = 0.0f;
        float u = ina ? 0.5f : fmaf(kf, hV, EPSF);
        evalV(u, w);
    }

    // ---------------- block reduction (4 waves of 64) ----------------
    for (int off = 32; off > 0; off >>= 1) {
        Lre += __shfl_down(Lre, off);
        LiP += __shfl_down(LiP, off);
        Vre += __shfl_down(Vre, off);
        ViP += __shfl_down(ViP, off);
    }
    __shared__ float4 wsum[4];
    const int lane = tid & 63;
    const int wid  = tid >> 6;
    if (lane == 0) wsum[wid] = make_float4(Lre, LiP, Vre, ViP);
    __syncthreads();
    if (tid == 0) {
        float4 t = wsum[0];
        t.x += wsum[1].x + wsum[2].x + wsum[3].x;
        t.y += wsum[1].y + wsum[2].y + wsum[3].y;
        t.z += wsum[1].z + wsum[2].z + wsum[3].z;
        t.w += wsum[1].w + wsum[2].w + wsum[3].w;

        const float twopi = 2.0f * PIF;
        const float sL = (2.0f / PIF) * zs * hL;
        const float sV = twopi * zs * hV;
        out[0 * B + bid] =  t.x * sL;
        out[1 * B + bid] = -t.y * sL;                 // Im = -(accumulated)
        out[2 * B + bid] =  t.z * sV - twopi / zs;
        out[3 * B + bid] = -t.w * sV;
    }
}

extern "C" void kernel_launch(void* const* d_in, const int* in_sizes, int n_in,
                              void* d_out, int out_size, void* d_ws, size_t ws_size,
                              hipStream_t stream) {
    const float* a  = (const float*)d_in[0];
    const float* b  = (const float*)d_in[1];
    const float* zs = (const float*)d_in[2];
    float* out = (float*)d_out;
    const int B = in_sizes[2];
    adsbh_kernel<<<B, 256, 0, stream>>>(a, b, zs, out, B);
}

// Round 8
// 67.130 us; speedup vs baseline: 2.5259x; 1.1567x over previous
//
#include <hip/hip_runtime.h>
#include <math.h>

#define NU_L 2000
#define NU_V 1500
#define EPSF 1e-6f
#define EPS2 1e-12f
#define PIF   3.14159265358979323846f
#define LOG2E 1.44269504088896340736f

__device__ __forceinline__ float exp2s(float x) { return __builtin_amdgcn_exp2f(x); }
__device__ __forceinline__ float rsqs(float x)  { return __builtin_amdgcn_rsqf(x); }
__device__ __forceinline__ float rcps(float x)  { return __builtin_amdgcn_rcpf(x); }
__device__ __forceinline__ float sqrts(float x) { return __builtin_amdgcn_sqrtf(x); }

__global__ __launch_bounds__(256) void adsbh_kernel(
    const float* __restrict__ pa, const float* __restrict__ pb,
    const float* __restrict__ zs_arr, float* __restrict__ out, int B)
{
    const int bid = blockIdx.x;
    const int tid = threadIdx.x & 255;

    // coefficient sets (pre-scaled by log2 e):
    //   a*: Pa (for f);  h*: Pb/2 (sqrt(g) in L);  c*: (Pa+Pb)/2 (sqrt(fg) in V)
    const float a0 = pa[0]*LOG2E, a1 = pa[1]*LOG2E, a2 = pa[2]*LOG2E,
                a3 = pa[3]*LOG2E, a4 = pa[4]*LOG2E;
    const float h0 = 0.5f*pb[0]*LOG2E, h1 = 0.5f*pb[1]*LOG2E, h2 = 0.5f*pb[2]*LOG2E,
                h3 = 0.5f*pb[3]*LOG2E, h4 = 0.5f*pb[4]*LOG2E;
    const float c0 = 0.5f*a0 + h0, c1 = 0.5f*a1 + h1, c2 = 0.5f*a2 + h2,
                c3 = 0.5f*a3 + h3, c4 = 0.5f*a4 + h4;

    const float zs  = zs_arr[bid];
    const float zs2 = zs * zs;
    const float zs4 = zs2 * zs2;
    const float Hs  = fmaf(a4, zs4, fmaf(zs2, fmaf(a3, zs, a2), fmaf(a1, zs, a0)));
    const float fzs = (1.0f - zs4) * exp2s(zs * Hs);

    const float hL = (1.0f - 2.0f * EPSF) / (float)(NU_L - 1);
    const float hV = (1.0f - 2.0f * EPSF) / (float)(NU_V - 1);

    float Lre = 0.0f, LiP = 0.0f, Vre = 0.0f, ViP = 0.0f;  // *iP = -Im

    // ---- L integrand eval, weight w (in units of hL); w=0 => masked ----
    // integrand = sqrt(g)/csqrt(denom); denom = num/D, D>0 real.
    // Reflected half-angle (P=|nx|+r, cancellation-free for all quadrants):
    //   scale = exp2(Ph-0.5)*sqrt(D/(omz4*P*r^2))
    //   nx>=0: (Re,-Im) = (P, sgn(ny)|ny|)*scale ; nx<0: (|ny|, sgn(ny)P)*scale
    auto evalL = [&](float u, float w) {
        float z = zs*u, z2 = z*z, z4 = z2*z2;
        float omz4 = 1.0f - z4;
        float pA  = fmaf(a1, z, a0), pA2 = fmaf(a3, z, a2);
        float hA  = fmaf(z2, pA2, pA); hA = fmaf(a4, z4, hA);
        float Pa  = z * hA;
        float pH  = fmaf(h1, z, h0), pH2 = fmaf(h3, z, h2);
        float hH  = fmaf(z2, pH2, pH); hH = fmaf(h4, z4, hH);
        float PhM = fmaf(z, hH, -0.5f);          // Ph - 0.5 (folds sqrt(1/2))
        float Ea  = exp2s(Pa);                   // T1
        float Eh  = exp2s(PhM);                  // T2
        float fz  = omz4 * Ea;
        float A   = zs4 * fz;
        float dx  = fmaf(z4, fzs, EPSF);
        float D   = fmaf(dx, dx, EPS2);
        float t1  = fmaf(A, dx, -D);
        float nx  = fmaf(EPSF, D, t1);           // A*dx - D(1-eps)
        float ny  = EPSF * (D - A);
        float r2  = fmaf(nx, nx, ny * ny);
        float ir  = rsqs(r2);                    // T3
        float r   = r2 * ir;
        float P   = fabsf(nx) + r;
        float W   = omz4 * (P * r2);
        float iW  = rcps(W);                     // T4
        float S   = sqrts(D * iW);               // T5
        float SS  = (S * Eh) * w;
        float cA  = P * SS, cB = fabsf(ny) * SS;
        bool  neg = nx < 0.0f;
        float re  = neg ? cB : cA;
        float ti  = neg ? cA : cB;
        Lre += re;
        LiP += copysignf(ti, ny);
    };

    // ---- V integrand eval: term = F/csqrt(inner) - 1, then /(z^2+eps(1+i))
    auto evalV = [&](float u, float w) {
        float z = zs*u, z2 = z*z, z4 = z2*z2;
        float omz4 = 1.0f - z4;
        float pA  = fmaf(a1, z, a0), pA2 = fmaf(a3, z, a2);
        float hA  = fmaf(z2, pA2, pA); hA = fmaf(a4, z4, hA);
        float Pa  = z * hA;
        float pC  = fmaf(c1, z, c0), pC2 = fmaf(c3, z, c2);
        float hC  = fmaf(z2, pC2, pC); hC = fmaf(c4, z4, hC);
        float PcM = fmaf(z, hC, -0.5f);          // Pc - 0.5 (folds sqrt(1/2))
        float Ea  = exp2s(Pa);                   // T1
        float Fs  = exp2s(PcM);                  // T2
        float fz  = omz4 * Ea;
        float Bv  = z4 * fzs;
        float dx  = fmaf(zs4, fz, EPSF);
        float D   = fmaf(dx, dx, EPS2);
        float t1  = fmaf(Bv, dx, -D);
        float nx  = fmaf(EPSF, D, -t1);          // D(1+eps) - Bv*dx
        float ny  = EPSF * (Bv + D);
        float r2  = fmaf(nx, nx, ny * ny);
        float ir  = rsqs(r2);                    // T3
        float r   = r2 * ir;
        float P   = fabsf(nx) + r;
        float W   = P * r2;
        float iW  = rcps(W);                     // T4
        float S   = sqrts(D * iW);               // T5
        float SS  = S * Fs;
        float cA  = P * SS, cB = fabsf(ny) * SS;
        bool  neg = nx < 0.0f;
        float wre = neg ? cB : cA;
        float wti = neg ? cA : cB;
        float tre = wre - 1.0f;
        float tiP = copysignf(wti, ny);          // -Im of csqrt-term
        float ddx = z2 + EPSF;
        float idn = rcps(fmaf(ddx, ddx, EPS2));  // T6
        float re  = fmaf(tre, ddx, -(tiP * EPSF)) * idn;
        float iP  = fmaf(tiP, ddx,   tre * EPSF) * idn;
        Vre = fmaf(w, re, Vre);
        ViP = fmaf(w, iP, ViP);
    };

    // ======== L: 245 nodes, ONE round ========
    // coarse k=16*t, t=0..117 (w: t=0 ->8, t=117 ->8.5, else 16)
    // fine  k=t+1755, t=118..244 (w: t=244 ->0.5, else 1)
    // weight sum = 8 + 116*16 + 8.5 + 126*1 + 0.5 = 1999  (= (N-1) h-units)
    {
        bool coarse = tid <= 117;
        bool act    = tid <= 244;
        int  k      = coarse ? (16 * tid) : (tid + 1755);
        float w     = coarse ? ((tid == 0) ? 8.0f : ((tid == 117) ? 8.5f : 16.0f))
                             : ((tid == 244) ? 0.5f : 1.0f);
        if (!act) w = 0.0f;
        float u = act ? fmaf((float)k, hL, EPSF) : 0.25f;
        evalL(u, w);
    }

    // ======== V: 345 nodes, 1 + 1/3 rounds ========
    // fine head k=t, t=0..128 (w: 0 ->0.5, 128 ->8.5, else 1)
    // coarse    k=16t-1920, t=129..205 (w: 205 ->8.5, else 16)
    // fine tail k=t+1155, t=206..255 (w=1), continued in round 1
    // weight sum = 0.5 + 127 + 8.5 + 76*16 + 8.5 + 138 + 0.5 = 1499
    {
        int k; float w;
        if (tid <= 128) {
            k = tid;
            w = (tid == 0) ? 0.5f : ((tid == 128) ? 8.5f : 1.0f);
        } else if (tid <= 205) {
            k = 16 * tid - 1920;                 // 144..1360
            w = (tid == 205) ? 8.5f : 16.0f;
        } else {
            k = tid + 1155;                      // 1361..1410
            w = 1.0f;
        }
        evalV(fmaf((float)k, hV, EPSF), w);
    }
    if (tid <= 88) {                             // waves 2,3 skip entirely
        int k   = tid + 1411;                    // 1411..1499
        float w = (tid == 88) ? 0.5f : 1.0f;
        evalV(fmaf((float)k, hV, EPSF), w);
    }

    // ---------------- block reduction (4 waves of 64) ----------------
    for (int off = 32; off > 0; off >>= 1) {
        Lre += __shfl_down(Lre, off);
        LiP += __shfl_down(LiP, off);
        Vre += __shfl_down(Vre, off);
        ViP += __shfl_down(ViP, off);
    }
    __shared__ float4 wsum[4];
    const int lane = tid & 63;
    const int wid  = tid >> 6;
    if (lane == 0) wsum[wid] = make_float4(Lre, LiP, Vre, ViP);
    __syncthreads();
    if (tid == 0) {
        float4 t = wsum[0];
        t.x += wsum[1].x + wsum[2].x + wsum[3].x;
        t.y += wsum[1].y + wsum[2].y + wsum[3].y;
        t.z += wsum[1].z + wsum[2].z + wsum[3].z;
        t.w += wsum[1].w + wsum[2].w + wsum[3].w;

        const float twopi = 2.0f * PIF;
        const float sL = (2.0f / PIF) * zs * hL;
        const float sV = twopi * zs * hV;
        out[0 * B + bid] =  t.x * sL;
        out[1 * B + bid] = -t.y * sL;                 // Im = -(accumulated)
        out[2 * B + bid] =  t.z * sV - twopi / zs;
        out[3 * B + bid] = -t.w * sV;
    }
}

extern "C" void kernel_launch(void* const* d_in, const int* in_sizes, int n_in,
                              void* d_out, int out_size, void* d_ws, size_t ws_size,
                              hipStream_t stream) {
    const float* a  = (const float*)d_in[0];
    const float* b  = (const float*)d_in[1];
    const float* zs = (const float*)d_in[2];
    float* out = (float*)d_out;
    const int B = in_sizes[2];
    adsbh_kernel<<<B, 256, 0, stream>>>(a, b, zs, out, B);
}

// Round 9
// 61.998 us; speedup vs baseline: 2.7350x; 1.0828x over previous
//
#include <hip/hip_runtime.h>
#include <math.h>

#define NU_L 2000
#define NU_V 1500
#define EPSF 1e-6f
#define EPS2 1e-12f
#define PIF   3.14159265358979323846f
#define LOG2E 1.44269504088896340736f

__device__ __forceinline__ float exp2s(float x) { return __builtin_amdgcn_exp2f(x); }
__device__ __forceinline__ float rsqs(float x)  { return __builtin_amdgcn_rsqf(x); }
__device__ __forceinline__ float rcps(float x)  { return __builtin_amdgcn_rcpf(x); }
__device__ __forceinline__ float sqrts(float x) { return __builtin_amdgcn_sqrtf(x); }

// One wave (64 lanes) per zs element: no LDS, no barriers, wave-local reduce.
__global__ __launch_bounds__(256) void adsbh_kernel(
    const float* __restrict__ pa, const float* __restrict__ pb,
    const float* __restrict__ zs_arr, float* __restrict__ out, int B)
{
    const int wid  = (threadIdx.x >> 6) & 3;
    const int lane = threadIdx.x & 63;
    const int zi   = blockIdx.x * 4 + wid;
    if (zi >= B) return;

    // coefficient sets (pre-scaled by log2 e):
    //   a*: Pa (for f);  h*: Pb/2 (sqrt(g) in L);  c*: (Pa+Pb)/2 (sqrt(fg) in V)
    const float a0 = pa[0]*LOG2E, a1 = pa[1]*LOG2E, a2 = pa[2]*LOG2E,
                a3 = pa[3]*LOG2E, a4 = pa[4]*LOG2E;
    const float h0 = 0.5f*pb[0]*LOG2E, h1 = 0.5f*pb[1]*LOG2E, h2 = 0.5f*pb[2]*LOG2E,
                h3 = 0.5f*pb[3]*LOG2E, h4 = 0.5f*pb[4]*LOG2E;
    const float c0 = 0.5f*a0 + h0, c1 = 0.5f*a1 + h1, c2 = 0.5f*a2 + h2,
                c3 = 0.5f*a3 + h3, c4 = 0.5f*a4 + h4;

    const float zs  = zs_arr[zi];
    const float zs2 = zs * zs;
    const float zs4 = zs2 * zs2;
    const float Hs  = fmaf(a4, zs4, fmaf(zs2, fmaf(a3, zs, a2), fmaf(a1, zs, a0)));
    const float fzs = (1.0f - zs4) * exp2s(zs * Hs);

    const float hL = (1.0f - 2.0f * EPSF) / (float)(NU_L - 1);
    const float hV = (1.0f - 2.0f * EPSF) / (float)(NU_V - 1);

    float Lre = 0.0f, LiP = 0.0f, Vre = 0.0f, ViP = 0.0f;  // *iP = -Im

    // ---- L integrand eval, weight w (in units of hL); w=0 => masked ----
    // Reflected half-angle (P=|nx|+r) — cancellation-free in all quadrants.
    auto evalL = [&](float u, float w) {
        float z = zs*u, z2 = z*z, z4 = z2*z2;
        float omz4 = 1.0f - z4;
        float pA  = fmaf(a1, z, a0), pA2 = fmaf(a3, z, a2);
        float hA  = fmaf(z2, pA2, pA); hA = fmaf(a4, z4, hA);
        float Pa  = z * hA;
        float pH  = fmaf(h1, z, h0), pH2 = fmaf(h3, z, h2);
        float hH  = fmaf(z2, pH2, pH); hH = fmaf(h4, z4, hH);
        float PhM = fmaf(z, hH, -0.5f);          // Ph - 0.5 (folds sqrt(1/2))
        float Ea  = exp2s(Pa);
        float Eh  = exp2s(PhM);
        float fz  = omz4 * Ea;
        float A   = zs4 * fz;
        float dx  = fmaf(z4, fzs, EPSF);
        float D   = fmaf(dx, dx, EPS2);
        float t1  = fmaf(A, dx, -D);
        float nx  = fmaf(EPSF, D, t1);           // A*dx - D(1-eps)
        float ny  = EPSF * (D - A);
        float r2  = fmaf(nx, nx, ny * ny);
        float ir  = rsqs(r2);
        float r   = r2 * ir;
        float P   = fabsf(nx) + r;
        float W   = omz4 * (P * r2);
        float iW  = rcps(W);
        float S   = sqrts(D * iW);
        float SS  = (S * Eh) * w;
        float cA  = P * SS, cB = fabsf(ny) * SS;
        bool  neg = nx < 0.0f;
        float re  = neg ? cB : cA;
        float ti  = neg ? cA : cB;
        Lre += re;
        LiP += copysignf(ti, ny);
    };

    // ---- V integrand eval: term = F/csqrt(inner) - 1, then /(z^2+eps(1+i))
    auto evalV = [&](float u, float w) {
        float z = zs*u, z2 = z*z, z4 = z2*z2;
        float omz4 = 1.0f - z4;
        float pA  = fmaf(a1, z, a0), pA2 = fmaf(a3, z, a2);
        float hA  = fmaf(z2, pA2, pA); hA = fmaf(a4, z4, hA);
        float Pa  = z * hA;
        float pC  = fmaf(c1, z, c0), pC2 = fmaf(c3, z, c2);
        float hC  = fmaf(z2, pC2, pC); hC = fmaf(c4, z4, hC);
        float PcM = fmaf(z, hC, -0.5f);          // Pc - 0.5 (folds sqrt(1/2))
        float Ea  = exp2s(Pa);
        float Fs  = exp2s(PcM);
        float fz  = omz4 * Ea;
        float Bv  = z4 * fzs;
        float dx  = fmaf(zs4, fz, EPSF);
        float D   = fmaf(dx, dx, EPS2);
        float t1  = fmaf(Bv, dx, -D);
        float nx  = fmaf(EPSF, D, -t1);          // D(1+eps) - Bv*dx
        float ny  = EPSF * (Bv + D);
        float r2  = fmaf(nx, nx, ny * ny);
        float ir  = rsqs(r2);
        float r   = r2 * ir;
        float P   = fabsf(nx) + r;
        float W   = P * r2;
        float iW  = rcps(W);
        float S   = sqrts(D * iW);
        float SS  = S * Fs;
        float cA  = P * SS, cB = fabsf(ny) * SS;
        bool  neg = nx < 0.0f;
        float wre = neg ? cB : cA;
        float wti = neg ? cA : cB;
        float tre = wre - 1.0f;
        float tiP = copysignf(wti, ny);
        float ddx = z2 + EPSF;
        float idn = rcps(fmaf(ddx, ddx, EPS2));
        float re  = fmaf(tre, ddx, -(tiP * EPSF)) * idn;
        float iP  = fmaf(tiP, ddx,   tre * EPSF) * idn;
        Vre = fmaf(w, re, Vre);
        ViP = fmaf(w, iP, ViP);
    };

    // L node table (125 nodes): idx 0..60 coarse k=32*idx
    //   (w: 16 / 32 / 24 at idx60); idx 61..124 fine k=idx+1875 (1936..1999)
    //   (w: 8.5 at idx61 / 1 / 0.5 at idx124).
    //   weight sum = 16 + 59*32 + 24 + 8.5 + 62 + 0.5 = 1999  (h-units)
    auto nodeL = [&](int idx) {
        bool coarse = idx <= 60;
        int  k = coarse ? (32 * idx) : (idx + 1875);
        float w = coarse ? ((idx == 0) ? 16.0f : ((idx == 60) ? 24.0f : 32.0f))
                         : ((idx == 61) ? 8.5f : ((idx == 124) ? 0.5f : 1.0f));
        bool act = idx <= 124;
        evalL(act ? fmaf((float)k, hL, EPSF) : 0.25f, act ? w : 0.0f);
    };
    // V node table (183 nodes): idx 0..96 fine k=idx (w: 0.5 / 1 / 16.5 at 96);
    //   idx 97..138 coarse k=32*idx-2976 (128..1440) (w: 32 / 24 at 138);
    //   idx 139..182 fine k=idx+1317 (1456..1499) (w: 8.5 at 139 / 1 / 0.5 at 182).
    //   weight sum = 0.5 + 95 + 16.5 + 41*32 + 24 + 8.5 + 42 + 0.5 = 1499
    auto nodeV = [&](int idx) {
        int k; float w;
        if (idx <= 96)       { k = idx;              w = (idx == 0) ? 0.5f : ((idx == 96) ? 16.5f : 1.0f); }
        else if (idx <= 138) { k = 32 * idx - 2976;  w = (idx == 138) ? 24.0f : 32.0f; }
        else                 { k = idx + 1317;       w = (idx == 139) ? 8.5f : ((idx == 182) ? 0.5f : 1.0f); }
        bool act = idx <= 182;
        evalV(act ? fmaf((float)k, hV, EPSF) : 0.25f, act ? w : 0.0f);
    };

    nodeL(lane);            // 0..63
    nodeL(lane + 64);       // 64..127 (active <= 124)
    nodeV(lane);            // 0..63
    nodeV(lane + 64);       // 64..127
    nodeV(lane + 128);      // 128..191 (active <= 182)

    // ---------------- wave reduction (64 lanes) ----------------
    for (int off = 32; off > 0; off >>= 1) {
        Lre += __shfl_down(Lre, off);
        LiP += __shfl_down(LiP, off);
        Vre += __shfl_down(Vre, off);
        ViP += __shfl_down(ViP, off);
    }
    if (lane == 0) {
        const float twopi = 2.0f * PIF;
        const float sL = (2.0f / PIF) * zs * hL;
        const float sV = twopi * zs * hV;
        out[0 * B + zi] =  Lre * sL;
        out[1 * B + zi] = -LiP * sL;                 // Im = -(accumulated)
        out[2 * B + zi] =  Vre * sV - twopi / zs;
        out[3 * B + zi] = -ViP * sV;
    }
}

extern "C" void kernel_launch(void* const* d_in, const int* in_sizes, int n_in,
                              void* d_out, int out_size, void* d_ws, size_t ws_size,
                              hipStream_t stream) {
    const float* a  = (const float*)d_in[0];
    const float* b  = (const float*)d_in[1];
    const float* zs = (const float*)d_in[2];
    float* out = (float*)d_out;
    const int B = in_sizes[2];
    adsbh_kernel<<<(B + 3) / 4, 256, 0, stream>>>(a, b, zs, out, B);
}

// Round 10
// 60.449 us; speedup vs baseline: 2.8051x; 1.0256x over previous
//
#include <hip/hip_runtime.h>
#include <math.h>

#define NU_L 2000
#define NU_V 1500
#define EPSF 1e-6f
#define EPS2 1e-12f
#define PIF   3.14159265358979323846f
#define LOG2E 1.44269504088896340736f

__device__ __forceinline__ float exp2s(float x) { return __builtin_amdgcn_exp2f(x); }
__device__ __forceinline__ float rsqs(float x)  { return __builtin_amdgcn_rsqf(x); }
__device__ __forceinline__ float rcps(float x)  { return __builtin_amdgcn_rcpf(x); }
__device__ __forceinline__ float sqrts(float x) { return __builtin_amdgcn_sqrtf(x); }

// One wave (64 lanes) per zs element: no LDS, no barriers, wave-local reduce.
// Graded quadrature meshes (exactly the reference's nodes, subset + trapezoid
// weights; weight sums = 1999*hL / 1499*hV exactly).
__global__ __launch_bounds__(256) void adsbh_kernel(
    const float* __restrict__ pa, const float* __restrict__ pb,
    const float* __restrict__ zs_arr, float* __restrict__ out, int B)
{
    const int wid  = (threadIdx.x >> 6) & 3;
    const int lane = threadIdx.x & 63;
    const int zi   = blockIdx.x * 4 + wid;
    if (zi >= B) return;

    // coefficient sets (pre-scaled by log2 e):
    //   a*: Pa (for f);  h*: Pb/2 (sqrt(g) in L);  c*: (Pa+Pb)/2 (sqrt(fg) in V)
    const float a0 = pa[0]*LOG2E, a1 = pa[1]*LOG2E, a2 = pa[2]*LOG2E,
                a3 = pa[3]*LOG2E, a4 = pa[4]*LOG2E;
    const float h0 = 0.5f*pb[0]*LOG2E, h1 = 0.5f*pb[1]*LOG2E, h2 = 0.5f*pb[2]*LOG2E,
                h3 = 0.5f*pb[3]*LOG2E, h4 = 0.5f*pb[4]*LOG2E;
    const float c0 = 0.5f*a0 + h0, c1 = 0.5f*a1 + h1, c2 = 0.5f*a2 + h2,
                c3 = 0.5f*a3 + h3, c4 = 0.5f*a4 + h4;

    const float zs  = zs_arr[zi];
    const float zs2 = zs * zs;
    const float zs4 = zs2 * zs2;
    const float Hs  = fmaf(a4, zs4, fmaf(zs2, fmaf(a3, zs, a2), fmaf(a1, zs, a0)));
    const float fzs = (1.0f - zs4) * exp2s(zs * Hs);

    const float hL = (1.0f - 2.0f * EPSF) / (float)(NU_L - 1);
    const float hV = (1.0f - 2.0f * EPSF) / (float)(NU_V - 1);

    float Lre = 0.0f, LiP = 0.0f, Vre = 0.0f, ViP = 0.0f;  // *iP = -Im

    // ---- L integrand eval, weight w (in units of hL); w=0 => masked ----
    // Reflected half-angle (P=|nx|+r) — cancellation-free in all quadrants.
    auto evalL = [&](float u, float w) {
        float z = zs*u, z2 = z*z, z4 = z2*z2;
        float omz4 = 1.0f - z4;
        float pA  = fmaf(a1, z, a0), pA2 = fmaf(a3, z, a2);
        float hA  = fmaf(z2, pA2, pA); hA = fmaf(a4, z4, hA);
        float Pa  = z * hA;
        float pH  = fmaf(h1, z, h0), pH2 = fmaf(h3, z, h2);
        float hH  = fmaf(z2, pH2, pH); hH = fmaf(h4, z4, hH);
        float PhM = fmaf(z, hH, -0.5f);          // Ph - 0.5 (folds sqrt(1/2))
        float Ea  = exp2s(Pa);
        float Eh  = exp2s(PhM);
        float fz  = omz4 * Ea;
        float A   = zs4 * fz;
        float dx  = fmaf(z4, fzs, EPSF);
        float D   = fmaf(dx, dx, EPS2);
        float t1  = fmaf(A, dx, -D);
        float nx  = fmaf(EPSF, D, t1);           // A*dx - D(1-eps)
        float ny  = EPSF * (D - A);
        float r2  = fmaf(nx, nx, ny * ny);
        float ir  = rsqs(r2);
        float r   = r2 * ir;
        float P   = fabsf(nx) + r;
        float W   = omz4 * (P * r2);
        float iW  = rcps(W);
        float S   = sqrts(D * iW);
        float SS  = (S * Eh) * w;
        float cA  = P * SS, cB = fabsf(ny) * SS;
        bool  neg = nx < 0.0f;
        float re  = neg ? cB : cA;
        float ti  = neg ? cA : cB;
        Lre += re;
        LiP += copysignf(ti, ny);
    };

    // ---- V integrand eval: term = F/csqrt(inner) - 1, then /(z^2+eps(1+i))
    auto evalV = [&](float u, float w) {
        float z = zs*u, z2 = z*z, z4 = z2*z2;
        float omz4 = 1.0f - z4;
        float pA  = fmaf(a1, z, a0), pA2 = fmaf(a3, z, a2);
        float hA  = fmaf(z2, pA2, pA); hA = fmaf(a4, z4, hA);
        float Pa  = z * hA;
        float pC  = fmaf(c1, z, c0), pC2 = fmaf(c3, z, c2);
        float hC  = fmaf(z2, pC2, pC); hC = fmaf(c4, z4, hC);
        float PcM = fmaf(z, hC, -0.5f);          // Pc - 0.5 (folds sqrt(1/2))
        float Ea  = exp2s(Pa);
        float Fs  = exp2s(PcM);
        float fz  = omz4 * Ea;
        float Bv  = z4 * fzs;
        float dx  = fmaf(zs4, fz, EPSF);
        float D   = fmaf(dx, dx, EPS2);
        float t1  = fmaf(Bv, dx, -D);
        float nx  = fmaf(EPSF, D, -t1);          // D(1+eps) - Bv*dx
        float ny  = EPSF * (Bv + D);
        float r2  = fmaf(nx, nx, ny * ny);
        float ir  = rsqs(r2);
        float r   = r2 * ir;
        float P   = fabsf(nx) + r;
        float W   = P * r2;
        float iW  = rcps(W);
        float S   = sqrts(D * iW);
        float SS  = S * Fs;
        float cA  = P * SS, cB = fabsf(ny) * SS;
        bool  neg = nx < 0.0f;
        float wre = neg ? cB : cA;
        float wti = neg ? cA : cB;
        float tre = wre - 1.0f;
        float tiP = copysignf(wti, ny);
        float ddx = z2 + EPSF;
        float idn = rcps(fmaf(ddx, ddx, EPS2));
        float re  = fmaf(tre, ddx, -(tiP * EPSF)) * idn;
        float iP  = fmaf(tiP, ddx,   tre * EPSF) * idn;
        Vre = fmaf(w, re, Vre);
        ViP = fmaf(w, iP, ViP);
    };

    // ======== L: 61 nodes, ONE round ========
    // idx 0..29:  k=64*idx        (w: 32 / 64 / 36 at idx29)
    // idx 30..45: k=8*idx+1624    (1864..1984; w: 8 / 4.5 at idx45)
    // idx 46..60: k=idx+1939      (1985..1999; w: 1 / 0.5 at idx60)
    // sum = 32 + 28*64 + 36 + 15*8 + 4.5 + 14 + 0.5 = 1999
    {
        int idx = lane;
        int k; float w; bool act = idx <= 60;
        if (idx <= 29)      { k = 64*idx;       w = (idx==0) ? 32.0f : ((idx==29) ? 36.0f : 64.0f); }
        else if (idx <= 45) { k = 8*idx + 1624; w = (idx==45) ? 4.5f : 8.0f; }
        else                { k = idx + 1939;   w = (idx==60) ? 0.5f : 1.0f; }
        evalL(act ? fmaf((float)k, hL, EPSF) : 0.25f, act ? w : 0.0f);
    }

    // ======== V: 115 nodes, TWO rounds ========
    // idx 0..15:   k=idx          (w: 0.5 / 1 / 1.5 at idx15)
    // idx 16..31:  k=2*idx-15     (17..47;   w: 2 / 3 at idx31)
    // idx 32..47:  k=4*idx-77     (51..111;  w: 4 / 18 at idx47)
    // idx 48..86:  k=32*idx-1393  (143..1359; w: 32 / 20 at idx86)
    // idx 87..102: k=8*idx+671    (1367..1487; w: 8 / 4.5 at idx102)
    // idx 103..114:k=idx+1385     (1488..1499; w: 1 / 0.5 at idx114)
    // sum = 0.5+14+1.5 + 30+3 + 60+18 + 38*32+20 + 120+4.5 + 11+0.5 = 1499
    auto nodeV = [&](int idx) {
        int k; float w; bool act = idx <= 114;
        if (idx <= 15)       { k = idx;            w = (idx==0) ? 0.5f : ((idx==15) ? 1.5f : 1.0f); }
        else if (idx <= 31)  { k = 2*idx - 15;     w = (idx==31) ? 3.0f : 2.0f; }
        else if (idx <= 47)  { k = 4*idx - 77;     w = (idx==47) ? 18.0f : 4.0f; }
        else if (idx <= 86)  { k = 32*idx - 1393;  w = (idx==86) ? 20.0f : 32.0f; }
        else if (idx <= 102) { k = 8*idx + 671;    w = (idx==102) ? 4.5f : 8.0f; }
        else                 { k = idx + 1385;     w = (idx==114) ? 0.5f : 1.0f; }
        evalV(act ? fmaf((float)k, hV, EPSF) : 0.25f, act ? w : 0.0f);
    };
    nodeV(lane);
    nodeV(lane + 64);

    // ---------------- wave reduction (64 lanes) ----------------
    for (int off = 32; off > 0; off >>= 1) {
        Lre += __shfl_down(Lre, off);
        LiP += __shfl_down(LiP, off);
        Vre += __shfl_down(Vre, off);
        ViP += __shfl_down(ViP, off);
    }
    if (lane == 0) {
        const float twopi = 2.0f * PIF;
        const float sL = (2.0f / PIF) * zs * hL;
        const float sV = twopi * zs * hV;
        out[0 * B + zi] =  Lre * sL;
        out[1 * B + zi] = -LiP * sL;                 // Im = -(accumulated)
        out[2 * B + zi] =  Vre * sV - twopi / zs;
        out[3 * B + zi] = -ViP * sV;
    }
}

extern "C" void kernel_launch(void* const* d_in, const int* in_sizes, int n_in,
                              void* d_out, int out_size, void* d_ws, size_t ws_size,
                              hipStream_t stream) {
    const float* a  = (const float*)d_in[0];
    const float* b  = (const float*)d_in[1];
    const float* zs = (const float*)d_in[2];
    float* out = (float*)d_out;
    const int B = in_sizes[2];
    adsbh_kernel<<<(B + 3) / 4, 256, 0, stream>>>(a, b, zs, out, B);
}